// Round 4
// baseline (132.386 us; speedup 1.0000x reference)
//
#include <hip/hip_runtime.h>
#include <hip/hip_bf16.h>
#include <stdint.h>

typedef short s16x8 __attribute__((ext_vector_type(8)));
typedef float f32x4 __attribute__((ext_vector_type(4)));

#define NH    32
#define NKVH  8
#define GQ    4
#define HD    128
#define QBLK  64
#define KVBLK 64

static __device__ __forceinline__ ushort f2bf(float f) {
  return __bfloat16_as_ushort(__float2bfloat16(f));
}

static __device__ __forceinline__ int swzV(int d) {
  return (((d & 7) ^ ((d >> 4) & 7)) << 3);
}

// raw barrier: LDS visibility only -- no vmcnt(0) drain, prefetch stays in flight (T4)
#define TILE_BARRIER()                                          \
  do {                                                          \
    asm volatile("s_waitcnt lgkmcnt(0)" ::: "memory");          \
    __builtin_amdgcn_s_barrier();                               \
    __builtin_amdgcn_sched_barrier(0);                          \
  } while (0)

__global__ void __launch_bounds__(512, 2)
attn_doc_causal(const float* __restrict__ qg, const float* __restrict__ kg,
                const float* __restrict__ vg, float* __restrict__ og,
                int S, int L) {
  __shared__ ushort Klds[2][KVBLK * HD];   // [buf][kv][d], ^((kv&7)<<3)
  __shared__ ushort Vt[2][HD * KVBLK];     // [buf][d][kv], ^swzV(d)
  __shared__ ushort Plds[8][32 * KVBLK];   // per-wave [q][kv], ^(((q>>1)&7)<<3)

  const int tid  = threadIdx.x;
  const int lane = tid & 63;
  const int wid  = tid >> 6;
  const int col  = lane & 15;
  const int hi   = lane >> 4;
  const int hq   = wid & 3;
  const int qh   = wid >> 2;
  const int bid  = blockIdx.x;
  const int kvh  = bid & 7;                 // head-aligned XCD mapping
  const int nq   = L / QBLK;
  const int npair= nq >> 1;
  const int pidx = bid >> 3;
  const int doc  = pidx / npair;
  const int ipr  = pidx % npair;
  const int doc0 = doc * L;
  const int h    = kvh * GQ + hq;

  const int qt0   = nq - 1 - ipr;           // big q-tile first
  const int qt1   = ipr;                    // small q-tile second
  const int nt0   = qt0 + 1;
  const int total = nt0 + qt1 + 1;          // == nq + 1, uniform across blocks
  const int qw0   = doc0 + qt0 * QBLK + qh * 32;
  const int qw1   = doc0 + qt1 * QBLK + qh * 32;

  const float cs  = 0.08838834764831845f * 1.4426950408889634f;  // SCALE*log2(e)
  const float THR = 62.0f;

  const int srow = tid >> 3;                // 0..63
  const int scol = (tid & 7) << 4;          // 0..112
  const size_t kvstr = (size_t)(NKVH * HD);
  const float* kbase = kg + (size_t)kvh * HD + scol;
  const float* vbase = vg + (size_t)kvh * HD + scol;

  s16x8 qf[2][4];
  auto loadQ = [&](int qw) {
#pragma unroll
    for (int st = 0; st < 2; ++st) {
      const float* qrow = qg + (size_t)(qw + st * 16 + col) * (NH * HD) + h * HD + hi * 8;
#pragma unroll
      for (int dc = 0; dc < 4; ++dc) {
        float4 x = ((const float4*)(qrow + dc * 32))[0];
        float4 y = ((const float4*)(qrow + dc * 32))[1];
        s16x8 f;
        f[0] = (short)f2bf(x.x); f[1] = (short)f2bf(x.y);
        f[2] = (short)f2bf(x.z); f[3] = (short)f2bf(x.w);
        f[4] = (short)f2bf(y.x); f[5] = (short)f2bf(y.y);
        f[6] = (short)f2bf(y.z); f[7] = (short)f2bf(y.w);
        qf[st][dc] = f;
      }
    }
  };

  float4 k0, k1, k2, k3, v0, v1, v2, v3;
  auto loadKV = [&](int row) {
    const float* ks = kbase + (size_t)row * kvstr;
    const float* vs = vbase + (size_t)row * kvstr;
    k0 = ((const float4*)ks)[0]; k1 = ((const float4*)ks)[1];
    k2 = ((const float4*)ks)[2]; k3 = ((const float4*)ks)[3];
    v0 = ((const float4*)vs)[0]; v1 = ((const float4*)vs)[1];
    v2 = ((const float4*)vs)[2]; v3 = ((const float4*)vs)[3];
  };
  auto stage = [&](int b) {
    const int swK = (srow & 7) << 3;
    s16x8 lo, hb;
    lo[0]=(short)f2bf(k0.x); lo[1]=(short)f2bf(k0.y); lo[2]=(short)f2bf(k0.z); lo[3]=(short)f2bf(k0.w);
    lo[4]=(short)f2bf(k1.x); lo[5]=(short)f2bf(k1.y); lo[6]=(short)f2bf(k1.z); lo[7]=(short)f2bf(k1.w);
    hb[0]=(short)f2bf(k2.x); hb[1]=(short)f2bf(k2.y); hb[2]=(short)f2bf(k2.z); hb[3]=(short)f2bf(k2.w);
    hb[4]=(short)f2bf(k3.x); hb[5]=(short)f2bf(k3.y); hb[6]=(short)f2bf(k3.z); hb[7]=(short)f2bf(k3.w);
    *(s16x8*)&Klds[b][srow * HD + (scol ^ swK)]       = lo;
    *(s16x8*)&Klds[b][srow * HD + ((scol + 8) ^ swK)] = hb;
    float vv[16] = {v0.x,v0.y,v0.z,v0.w, v1.x,v1.y,v1.z,v1.w,
                    v2.x,v2.y,v2.z,v2.w, v3.x,v3.y,v3.z,v3.w};
#pragma unroll
    for (int j = 0; j < 16; ++j) {
      int d = scol + j;
      Vt[b][d * KVBLK + (srow ^ swzV(d))] = f2bf(vv[j]);
    }
  };

  f32x4 o[2][8];
  float m[2][4], ls[2][4];
  auto resetState = [&]() {
#pragma unroll
    for (int st = 0; st < 2; ++st) {
#pragma unroll
      for (int dt = 0; dt < 8; ++dt) { f32x4 z = {0.f, 0.f, 0.f, 0.f}; o[st][dt] = z; }
#pragma unroll
      for (int r = 0; r < 4; ++r) { m[st][r] = -__builtin_inff(); ls[st][r] = 0.f; }
    }
  };
  auto writeO = [&](int qw) {
#pragma unroll
    for (int st = 0; st < 2; ++st) {
      float rl[4];
#pragma unroll
      for (int r = 0; r < 4; ++r) rl[r] = 1.f / ls[st][r];
#pragma unroll
      for (int dt = 0; dt < 8; ++dt)
#pragma unroll
        for (int r = 0; r < 4; ++r) {
          int row = qw + st * 16 + hi * 4 + r;
          og[((size_t)h * S + row) * HD + dt * 16 + col] = o[st][dt][r] * rl[r];
        }
    }
  };

  // kv tile index for flat iteration i (two causal strips back to back)
  auto kvt = [&](int i) { return (i < nt0) ? i : (i - nt0); };

  loadQ(qw0);
  resetState();

  // ---- prologue: tile 0 -> buf0; issue tile-1 loads ----
  loadKV(doc0 + kvt(0) * KVBLK + srow);
  stage(0);
  if (total > 1) loadKV(doc0 + kvt(1) * KVBLK + srow);
  TILE_BARRIER();

  for (int i = 0; i < total; ++i) {
    const int cur = i & 1;

    // ---- stage tile i+1 into the idle buffer (overlaps this tile's compute) ----
    if (i + 1 < total) stage(cur ^ 1);
    // ---- issue tile i+2 global loads: full compute section of latency cover ----
    if (i + 2 < total) loadKV(doc0 + kvt(i + 2) * KVBLK + srow);

    // ---- QK^T from buf[cur] ----
    f32x4 sA[2][4];
#pragma unroll
    for (int kt = 0; kt < 4; ++kt) {
      const int r = kt * 16 + col;
      const int swr = (r & 7) << 3;
      s16x8 kf[4];
#pragma unroll
      for (int dc = 0; dc < 4; ++dc)
        kf[dc] = *(const s16x8*)&Klds[cur][r * HD + ((dc * 32 + hi * 8) ^ swr)];
      __builtin_amdgcn_s_setprio(1);
#pragma unroll
      for (int st = 0; st < 2; ++st) {
        f32x4 acc = {0.f, 0.f, 0.f, 0.f};
#pragma unroll
        for (int dc = 0; dc < 4; ++dc)
          acc = __builtin_amdgcn_mfma_f32_16x16x32_bf16(qf[st][dc], kf[dc], acc, 0, 0, 0);
        sA[st][kt] = acc;
      }
      __builtin_amdgcn_s_setprio(0);
    }

    // diagonal tiles: last iter of each phase
    if (i == nt0 - 1 || i == total - 1) {
#pragma unroll
      for (int st = 0; st < 2; ++st)
#pragma unroll
        for (int kt = 0; kt < 4; ++kt)
#pragma unroll
          for (int r = 0; r < 4; ++r) {
            int qr = qh * 32 + st * 16 + hi * 4 + r;
            int kc = kt * 16 + col;
            if (kc > qr) sA[st][kt][r] = -__builtin_inff();
          }
    }

    // ---- online softmax with defer-max ----
#pragma unroll
    for (int st = 0; st < 2; ++st) {
      float pm[4], ps[4];
#pragma unroll
      for (int r = 0; r < 4; ++r)
        pm[r] = fmaxf(fmaxf(sA[st][0][r], sA[st][1][r]), fmaxf(sA[st][2][r], sA[st][3][r]));
#pragma unroll
      for (int off = 1; off < 16; off <<= 1)
#pragma unroll
        for (int r = 0; r < 4; ++r) pm[r] = fmaxf(pm[r], __shfl_xor(pm[r], off));

      int need = 0;
#pragma unroll
      for (int r = 0; r < 4; ++r) need |= (pm[r] > m[st][r] + THR) ? 1 : 0;
      if (__any(need)) {
#pragma unroll
        for (int r = 0; r < 4; ++r) {
          float mn = fmaxf(m[st][r], pm[r]);
          float corr = __builtin_amdgcn_exp2f((m[st][r] - mn) * cs);
          m[st][r] = mn;
          ls[st][r] *= corr;
#pragma unroll
          for (int dt = 0; dt < 8; ++dt) o[st][dt][r] *= corr;
        }
      }
#pragma unroll
      for (int r = 0; r < 4; ++r) {
        float sum = 0.f;
#pragma unroll
        for (int kt = 0; kt < 4; ++kt) {
          float p = __builtin_amdgcn_exp2f((sA[st][kt][r] - m[st][r]) * cs);
          sA[st][kt][r] = p;
          sum += p;
        }
        ps[r] = sum;
      }
#pragma unroll
      for (int off = 1; off < 16; off <<= 1)
#pragma unroll
        for (int r = 0; r < 4; ++r) ps[r] += __shfl_xor(ps[r], off);
#pragma unroll
      for (int r = 0; r < 4; ++r) ls[st][r] += ps[r];
#pragma unroll
      for (int r = 0; r < 4; ++r) {
        int q = st * 16 + hi * 4 + r;
        int xq = ((q >> 1) & 7) << 3;
        ushort* dst = &Plds[wid][q * KVBLK];
        dst[(col)      ^ xq] = f2bf(sA[st][0][r]);
        dst[(16 + col) ^ xq] = f2bf(sA[st][1][r]);
        dst[(32 + col) ^ xq] = f2bf(sA[st][2][r]);
        dst[(48 + col) ^ xq] = f2bf(sA[st][3][r]);
      }
    }

    asm volatile("s_waitcnt lgkmcnt(0)" ::: "memory");  // wave-local P visibility
    __builtin_amdgcn_sched_barrier(0);                  // rule #18

    // ---- PV from buf[cur] ----
    s16x8 af[2][2];
#pragma unroll
    for (int st = 0; st < 2; ++st) {
      int q2 = st * 16 + col;
      int xq = ((q2 >> 1) & 7) << 3;
#pragma unroll
      for (int ksb = 0; ksb < 2; ++ksb)
        af[st][ksb] = *(const s16x8*)&Plds[wid][q2 * KVBLK + ((ksb * 32 + hi * 8) ^ xq)];
    }
#pragma unroll
    for (int dt = 0; dt < 8; ++dt) {
      int d2 = dt * 16 + col;
      int xv = swzV(d2);
#pragma unroll
      for (int ksb = 0; ksb < 2; ++ksb) {
        s16x8 vf = *(const s16x8*)&Vt[cur][d2 * KVBLK + ((ksb * 32 + hi * 8) ^ xv)];
        __builtin_amdgcn_s_setprio(1);
#pragma unroll
        for (int st = 0; st < 2; ++st)
          o[st][dt] = __builtin_amdgcn_mfma_f32_16x16x32_bf16(af[st][ksb], vf, o[st][dt], 0, 0, 0);
        __builtin_amdgcn_s_setprio(0);
      }
    }

    // ---- phase boundary: flush q-tile 0, switch to q-tile 1 ----
    if (i == nt0 - 1) {
      writeO(qw0);
      resetState();
      loadQ(qw1);
    }

    TILE_BARRIER();
  }

  writeO(qw1);
}

extern "C" void kernel_launch(void* const* d_in, const int* in_sizes, int n_in,
                              void* d_out, int out_size, void* d_ws, size_t ws_size,
                              hipStream_t stream) {
  const float* q = (const float*)d_in[0];
  const float* k = (const float*)d_in[1];
  const float* v = (const float*)d_in[2];
  float* out = (float*)d_out;
  const int S  = in_sizes[1] / (NKVH * HD);   // 4096
  const int nd = in_sizes[3] - 1;             // 4 docs
  const int L  = S / nd;                      // 1024
  const int nblk = (S / (2 * QBLK)) * NKVH;   // 256 = 1 block/CU
  attn_doc_causal<<<nblk, 512, 0, stream>>>(q, k, v, out, S, L);
}